// Round 2
// baseline (480.854 us; speedup 1.0000x reference)
//
#include <hip/hip_runtime.h>

#define TPB 256
#define GRID_BLOCKS 1024

typedef __attribute__((ext_vector_type(8))) short short8;
typedef __attribute__((ext_vector_type(4))) float floatx4;

__device__ __forceinline__ unsigned short bf_rne(float f){
    union { float f; unsigned u; } c; c.f = f;
    unsigned r = c.u + 0x7fffu + ((c.u >> 16) & 1u);
    return (unsigned short)(r >> 16);
}
// pack trunc-bf16 of (lo,hi) into one dword with a single v_perm_b32
__device__ __forceinline__ unsigned pack_bf(float lo, float hi){
    union { float f; unsigned u; } a, b; a.f = lo; b.f = hi;
    return __builtin_amdgcn_perm(b.u, a.u, 0x07060302u);
}

// ---------------------------------------------------------------------------
// pass1: transposed MFMA D = W^T * feats^T; per-channel stats in registers,
// mask branch (relu -> dot -> 2 shfl), pooled per-batch sums.
// R2 changes vs R1:
//  * REVERT interleave -> chunked per-wave tile ranges (R1 post-mortem:
//    interleave cost +30us; also made every s_pool entry non-zero -> 32x
//    more global atomics in the tail).
//  * 2 tiles (32 rows / 4KB) per iteration, depth-1 group prefetch: doubles
//    per-wave bytes in flight. R1 counters (HBM 10%, VALU 11%, Mfma 1.8%)
//    show a pure latency stall -- concurrency is the binding resource.
//  * launch_bounds(256,2): VGPR cap 256 so the ~110-reg working set fits
//    with no spill incentive; fixed grid 1024 (=4 blocks/CU at ~128 VGPR).
//  * keep boundary-search batch handling (no per-row bidx stream).
// ---------------------------------------------------------------------------
__global__ __launch_bounds__(TPB, 2) void pass1_kernel(
    const float* __restrict__ feats, const int* __restrict__ bidx,
    const float* __restrict__ w1, const float* __restrict__ b1,
    const float* __restrict__ mw1, const float* __restrict__ mb1,
    const float* __restrict__ mw2, const float* __restrict__ mb2,
    float* __restrict__ mask_out,
    float* __restrict__ ws_sum, float* __restrict__ ws_sq,
    float* __restrict__ ws_pool, int N, int B)
{
    __shared__ float s_pool[8][32];
    __shared__ float s_sum[32];
    __shared__ float s_sq[32];
    __shared__ int   s_lb[9];

    const int tid  = threadIdx.x;
    const int lane = tid & 63;
    const int p = lane & 15;               // point-in-tile (MFMA col)
    const int q = lane >> 4;               // k-group

    if (tid < 32){ s_sum[tid] = 0.f; s_sq[tid] = 0.f; }
    ((float*)s_pool)[tid] = 0.f;
    if (tid <= B){
        int lo = 0, hi = N;
        while (lo < hi){
            const int mid = (lo + hi) >> 1;
            if (bidx[mid] < tid) lo = mid + 1; else hi = mid;
        }
        s_lb[tid] = lo;                    // s_lb[B] == N
    }
    __syncthreads();

    short8 aw0, aw1, am0, am1;
    floatx4 ci_h0, ci_h1, ci_m0, ci_m1;
    float mw2v[8];
#pragma unroll
    for (int j = 0; j < 8; ++j){
        const int k = q * 8 + j;
        aw0[j] = (short)bf_rne(w1 [k * 32 + p]);
        aw1[j] = (short)bf_rne(w1 [k * 32 + 16 + p]);
        am0[j] = (short)bf_rne(mw1[k * 32 + p]);
        am1[j] = (short)bf_rne(mw1[k * 32 + 16 + p]);
    }
#pragma unroll
    for (int r = 0; r < 4; ++r){
        const int c0 = q * 4 + r, c1 = 16 + q * 4 + r;
        ci_h0[r] = b1[c0];  ci_h1[r] = b1[c1];
        ci_m0[r] = mb1[c0]; ci_m1[r] = mb1[c1];
        mw2v[r] = mw2[c0];  mw2v[4 + r] = mw2[c1];
    }
    const float mb2s = mb2[0];

    float hsum[8] = {0,0,0,0,0,0,0,0};
    float hsq [8] = {0,0,0,0,0,0,0,0};
    float pacc[8] = {0,0,0,0,0,0,0,0};

    const int npairs = (N + 31) >> 5;                    // 32-row groups
    const int nw  = gridDim.x * (TPB / 64);
    const int wid = blockIdx.x * (TPB / 64) + (tid >> 6);
    const int g0  = (int)((long)wid       * npairs / nw);
    const int g1  = (int)((long)(wid + 1) * npairs / nw);

    int curb = 0;
    {
        const int r0 = g0 << 5;
        while (curb < B - 1 && r0 >= s_lb[curb + 1]) curb++;
    }
    int lbn = s_lb[curb + 1];

    const float* rp = feats + (((size_t)g0) << 10) + (p << 5) + (q << 3);

    // prime group g0 (4KB: tile A rows r0+p, tile B rows r0+16+p)
    floatx4 vA0 = {0,0,0,0}, vA1 = {0,0,0,0}, vB0 = {0,0,0,0}, vB1 = {0,0,0,0};
    if (g0 < g1){
        const int rA = (g0 << 5) + p;
        if (rA < N){ const floatx4* vp = (const floatx4*)rp; vA0 = vp[0]; vA1 = vp[1]; }
        if (rA + 16 < N){ const floatx4* vp = (const floatx4*)(rp + 512); vB0 = vp[0]; vB1 = vp[1]; }
    }

    for (int g = g0; g < g1; ++g){
        // prefetch group g+1
        floatx4 nA0 = {0,0,0,0}, nA1 = {0,0,0,0}, nB0 = {0,0,0,0}, nB1 = {0,0,0,0};
        const float* np = rp + 1024;
        if (g + 1 < g1){
            const int rA = ((g + 1) << 5) + p;
            if (rA < N){ const floatx4* vp = (const floatx4*)np; nA0 = vp[0]; nA1 = vp[1]; }
            if (rA + 16 < N){ const floatx4* vp = (const floatx4*)(np + 512); nB0 = vp[0]; nB1 = vp[1]; }
        }

        const int r0 = g << 5;
        if (r0 >= lbn){                          // entered a new batch
#pragma unroll
            for (int j = 0; j < 8; ++j){
                if (pacc[j] != 0.f) atomicAdd(&s_pool[curb][q * 8 + j], pacc[j]);
                pacc[j] = 0.f;
            }
            do { curb++; } while (curb < B - 1 && r0 >= s_lb[curb + 1]);
            lbn = s_lb[curb + 1];
        }
        const bool slow = (r0 + 31 >= lbn) || (r0 + 31 >= N);

        if (!slow){
            pacc[0] += vA0[0] + vB0[0]; pacc[1] += vA0[1] + vB0[1];
            pacc[2] += vA0[2] + vB0[2]; pacc[3] += vA0[3] + vB0[3];
            pacc[4] += vA1[0] + vB1[0]; pacc[5] += vA1[1] + vB1[1];
            pacc[6] += vA1[2] + vB1[2]; pacc[7] += vA1[3] + vB1[3];
        } else {
            const int rA = r0 + p, rB = r0 + 16 + p;
            if (rA < N){
                int bl = curb;
                for (int c = curb + 1; c < B; ++c) bl += (rA >= s_lb[c]);
                atomicAdd(&s_pool[bl][q * 8 + 0], vA0[0]);
                atomicAdd(&s_pool[bl][q * 8 + 1], vA0[1]);
                atomicAdd(&s_pool[bl][q * 8 + 2], vA0[2]);
                atomicAdd(&s_pool[bl][q * 8 + 3], vA0[3]);
                atomicAdd(&s_pool[bl][q * 8 + 4], vA1[0]);
                atomicAdd(&s_pool[bl][q * 8 + 5], vA1[1]);
                atomicAdd(&s_pool[bl][q * 8 + 6], vA1[2]);
                atomicAdd(&s_pool[bl][q * 8 + 7], vA1[3]);
            }
            if (rB < N){
                int bl = curb;
                for (int c = curb + 1; c < B; ++c) bl += (rB >= s_lb[c]);
                atomicAdd(&s_pool[bl][q * 8 + 0], vB0[0]);
                atomicAdd(&s_pool[bl][q * 8 + 1], vB0[1]);
                atomicAdd(&s_pool[bl][q * 8 + 2], vB0[2]);
                atomicAdd(&s_pool[bl][q * 8 + 3], vB0[3]);
                atomicAdd(&s_pool[bl][q * 8 + 4], vB1[0]);
                atomicAdd(&s_pool[bl][q * 8 + 5], vB1[1]);
                atomicAdd(&s_pool[bl][q * 8 + 6], vB1[2]);
                atomicAdd(&s_pool[bl][q * 8 + 7], vB1[3]);
            }
        }

        short8 bfA, bfB;
        {
            unsigned* ba = (unsigned*)&bfA;
            ba[0] = pack_bf(vA0[0], vA0[1]); ba[1] = pack_bf(vA0[2], vA0[3]);
            ba[2] = pack_bf(vA1[0], vA1[1]); ba[3] = pack_bf(vA1[2], vA1[3]);
            unsigned* bb = (unsigned*)&bfB;
            bb[0] = pack_bf(vB0[0], vB0[1]); bb[1] = pack_bf(vB0[2], vB0[3]);
            bb[2] = pack_bf(vB1[0], vB1[1]); bb[3] = pack_bf(vB1[2], vB1[3]);
        }

        const floatx4 chA0 = __builtin_amdgcn_mfma_f32_16x16x32_bf16(aw0, bfA, ci_h0, 0, 0, 0);
        const floatx4 chA1 = __builtin_amdgcn_mfma_f32_16x16x32_bf16(aw1, bfA, ci_h1, 0, 0, 0);
        const floatx4 cmA0 = __builtin_amdgcn_mfma_f32_16x16x32_bf16(am0, bfA, ci_m0, 0, 0, 0);
        const floatx4 cmA1 = __builtin_amdgcn_mfma_f32_16x16x32_bf16(am1, bfA, ci_m1, 0, 0, 0);
        const floatx4 chB0 = __builtin_amdgcn_mfma_f32_16x16x32_bf16(aw0, bfB, ci_h0, 0, 0, 0);
        const floatx4 chB1 = __builtin_amdgcn_mfma_f32_16x16x32_bf16(aw1, bfB, ci_h1, 0, 0, 0);
        const floatx4 cmB0 = __builtin_amdgcn_mfma_f32_16x16x32_bf16(am0, bfB, ci_m0, 0, 0, 0);
        const floatx4 cmB1 = __builtin_amdgcn_mfma_f32_16x16x32_bf16(am1, bfB, ci_m1, 0, 0, 0);

        if (!slow){
#pragma unroll
            for (int r = 0; r < 4; ++r){
                const float a0 = chA0[r], b0 = chB0[r];
                hsum[r] += a0 + b0;
                hsq [r] = fmaf(a0, a0, fmaf(b0, b0, hsq[r]));
                const float a1 = chA1[r], b1v = chB1[r];
                hsum[4 + r] += a1 + b1v;
                hsq [4 + r] = fmaf(a1, a1, fmaf(b1v, b1v, hsq[4 + r]));
            }
        } else {
            if (r0 + p < N){
#pragma unroll
                for (int r = 0; r < 4; ++r){
                    const float a0 = chA0[r]; hsum[r]     += a0; hsq[r]     = fmaf(a0, a0, hsq[r]);
                    const float a1 = chA1[r]; hsum[4 + r] += a1; hsq[4 + r] = fmaf(a1, a1, hsq[4 + r]);
                }
            }
            if (r0 + 16 + p < N){
#pragma unroll
                for (int r = 0; r < 4; ++r){
                    const float b0 = chB0[r]; hsum[r]     += b0; hsq[r]     = fmaf(b0, b0, hsq[r]);
                    const float b1v = chB1[r]; hsum[4 + r] += b1v; hsq[4 + r] = fmaf(b1v, b1v, hsq[4 + r]);
                }
            }
        }

        float tmA = 0.f, tmB = 0.f;
#pragma unroll
        for (int r = 0; r < 4; ++r){
            tmA = fmaf(fmaxf(cmA0[r], 0.f), mw2v[r],     tmA);
            tmA = fmaf(fmaxf(cmA1[r], 0.f), mw2v[4 + r], tmA);
            tmB = fmaf(fmaxf(cmB0[r], 0.f), mw2v[r],     tmB);
            tmB = fmaf(fmaxf(cmB1[r], 0.f), mw2v[4 + r], tmB);
        }
        tmA += __shfl_xor(tmA, 16, 64); tmA += __shfl_xor(tmA, 32, 64);
        tmB += __shfl_xor(tmB, 16, 64); tmB += __shfl_xor(tmB, 32, 64);
        if (q == 0 && (r0 + p) < N)      mask_out[r0 + p]      = tmA + mb2s;
        if (q == 0 && (r0 + 16 + p) < N) mask_out[r0 + 16 + p] = tmB + mb2s;

        vA0 = nA0; vA1 = nA1; vB0 = nB0; vB1 = nB1; rp = np;
    }

    // final flush
#pragma unroll
    for (int j = 0; j < 8; ++j){
        if (pacc[j] != 0.f) atomicAdd(&s_pool[curb][q * 8 + j], pacc[j]);
    }
#pragma unroll
    for (int i = 0; i < 8; ++i){
        const int ch = (i >> 2) * 16 + q * 4 + (i & 3);
        atomicAdd(&s_sum[ch], hsum[i]);
        atomicAdd(&s_sq[ch],  hsq[i]);
    }
    __syncthreads();
    if (tid < 32){
        atomicAdd(&ws_sum[tid], s_sum[tid]);
        atomicAdd(&ws_sq[tid],  s_sq[tid]);
    }
    {
        const float pv = ((float*)s_pool)[tid];
        if (pv != 0.f) atomicAdd(&ws_pool[tid], pv);   // chunked -> mostly zero
    }
}

// ---------------------------------------------------------------------------
// pass2: per-block BN fold from global stats (kernel boundary = grid sync),
// block 0 writes pooled+iou; folded-weight MFMA, relu, 32x3 projection.
// Chunked ranges + 2-tile groups (same rationale as pass1).
// ---------------------------------------------------------------------------
__global__ __launch_bounds__(TPB, 2) void pass2_kernel(
    const float* __restrict__ feats, const int* __restrict__ bidx,
    const float* __restrict__ w1, const float* __restrict__ b1,
    const float* __restrict__ gamma, const float* __restrict__ beta,
    const float* __restrict__ w2, const float* __restrict__ b2,
    const float* __restrict__ iw, const float* __restrict__ ib,
    const float* __restrict__ ws_sum, const float* __restrict__ ws_sq,
    const float* __restrict__ ws_pool,
    float* __restrict__ pt_out, float* __restrict__ pooled_out,
    float* __restrict__ iou_out, int N, int B)
{
    __shared__ float s_sc[32];
    __shared__ float s_bp[32];
    __shared__ float s_pooled[256];
    __shared__ int   s_lb[33];

    const int tid  = threadIdx.x;
    const int lane = tid & 63;
    const int p = lane & 15;
    const int q = lane >> 4;

    if (tid < 32){
        const float invN = 1.f / (float)N;
        const float mu  = ws_sum[tid] * invN;
        const float var = ws_sq[tid] * invN - mu * mu;
        const float s   = gamma[tid] * rsqrtf(var + 1e-4f);
        s_sc[tid] = s;
        s_bp[tid] = (b1[tid] - mu) * s + beta[tid];
    }
    __syncthreads();

    if (blockIdx.x == 0){
        if (tid <= B){
            int lo = 0, hi = N;
            while (lo < hi){
                const int mid = (lo + hi) >> 1;
                if (bidx[mid] < tid) lo = mid + 1; else hi = mid;
            }
            s_lb[tid] = lo;
        }
        __syncthreads();
        if (tid < B * 32){
            const int bb = tid >> 5;
            const float cnt = fmaxf((float)(s_lb[bb + 1] - s_lb[bb]), 1.f);
            const float pv = ws_pool[tid] / cnt;
            s_pooled[tid]   = pv;
            pooled_out[tid] = pv;
        }
        __syncthreads();
        if (tid < B){
            float acc = ib[0];
#pragma unroll
            for (int i = 0; i < 32; ++i) acc = fmaf(s_pooled[tid * 32 + i], iw[i], acc);
            iou_out[tid] = acc;
        }
    }

    short8 pw0, pw1;
    floatx4 pc0, pc1;
    float w2v[24];
    const float sc0 = s_sc[p], sc1 = s_sc[16 + p];
#pragma unroll
    for (int j = 0; j < 8; ++j){
        const int k = q * 8 + j;
        pw0[j] = (short)bf_rne(w1[k * 32 + p]      * sc0);
        pw1[j] = (short)bf_rne(w1[k * 32 + 16 + p] * sc1);
    }
#pragma unroll
    for (int r = 0; r < 4; ++r){
        pc0[r] = s_bp[q * 4 + r];
        pc1[r] = s_bp[16 + q * 4 + r];
    }
#pragma unroll
    for (int i = 0; i < 8; ++i){
        const int ch = (i >> 2) * 16 + q * 4 + (i & 3);
        w2v[i]      = w2[ch * 3 + 0];
        w2v[8 + i]  = w2[ch * 3 + 1];
        w2v[16 + i] = w2[ch * 3 + 2];
    }
    const float b2v0 = b2[0], b2v1 = b2[1], b2v2 = b2[2];

    const int npairs = (N + 31) >> 5;
    const int nw  = gridDim.x * (TPB / 64);
    const int wid = blockIdx.x * (TPB / 64) + (tid >> 6);
    const int g0  = (int)((long)wid       * npairs / nw);
    const int g1  = (int)((long)(wid + 1) * npairs / nw);

    const float* rp = feats + (((size_t)g0) << 10) + (p << 5) + (q << 3);

    floatx4 vA0 = {0,0,0,0}, vA1 = {0,0,0,0}, vB0 = {0,0,0,0}, vB1 = {0,0,0,0};
    if (g0 < g1){
        const int rA = (g0 << 5) + p;
        if (rA < N){ const floatx4* vp = (const floatx4*)rp; vA0 = vp[0]; vA1 = vp[1]; }
        if (rA + 16 < N){ const floatx4* vp = (const floatx4*)(rp + 512); vB0 = vp[0]; vB1 = vp[1]; }
    }

    for (int g = g0; g < g1; ++g){
        floatx4 nA0 = {0,0,0,0}, nA1 = {0,0,0,0}, nB0 = {0,0,0,0}, nB1 = {0,0,0,0};
        const float* np = rp + 1024;
        if (g + 1 < g1){
            const int rA = ((g + 1) << 5) + p;
            if (rA < N){ const floatx4* vp = (const floatx4*)np; nA0 = vp[0]; nA1 = vp[1]; }
            if (rA + 16 < N){ const floatx4* vp = (const floatx4*)(np + 512); nB0 = vp[0]; nB1 = vp[1]; }
        }

        short8 bfA, bfB;
        {
            unsigned* ba = (unsigned*)&bfA;
            ba[0] = pack_bf(vA0[0], vA0[1]); ba[1] = pack_bf(vA0[2], vA0[3]);
            ba[2] = pack_bf(vA1[0], vA1[1]); ba[3] = pack_bf(vA1[2], vA1[3]);
            unsigned* bb = (unsigned*)&bfB;
            bb[0] = pack_bf(vB0[0], vB0[1]); bb[1] = pack_bf(vB0[2], vB0[3]);
            bb[2] = pack_bf(vB1[0], vB1[1]); bb[3] = pack_bf(vB1[2], vB1[3]);
        }

        const floatx4 cA0 = __builtin_amdgcn_mfma_f32_16x16x32_bf16(pw0, bfA, pc0, 0, 0, 0);
        const floatx4 cA1 = __builtin_amdgcn_mfma_f32_16x16x32_bf16(pw1, bfA, pc1, 0, 0, 0);
        const floatx4 cB0 = __builtin_amdgcn_mfma_f32_16x16x32_bf16(pw0, bfB, pc0, 0, 0, 0);
        const floatx4 cB1 = __builtin_amdgcn_mfma_f32_16x16x32_bf16(pw1, bfB, pc1, 0, 0, 0);

        float sA0 = 0.f, sA1 = 0.f, sA2 = 0.f, sB0 = 0.f, sB1 = 0.f, sB2 = 0.f;
#pragma unroll
        for (int r = 0; r < 4; ++r){
            const float a0 = fmaxf(cA0[r], 0.f);
            const float a1 = fmaxf(cA1[r], 0.f);
            sA0 = fmaf(a0, w2v[r],      sA0); sA0 = fmaf(a1, w2v[4 + r],  sA0);
            sA1 = fmaf(a0, w2v[8 + r],  sA1); sA1 = fmaf(a1, w2v[12 + r], sA1);
            sA2 = fmaf(a0, w2v[16 + r], sA2); sA2 = fmaf(a1, w2v[20 + r], sA2);
            const float b0 = fmaxf(cB0[r], 0.f);
            const float b1v = fmaxf(cB1[r], 0.f);
            sB0 = fmaf(b0, w2v[r],      sB0); sB0 = fmaf(b1v, w2v[4 + r],  sB0);
            sB1 = fmaf(b0, w2v[8 + r],  sB1); sB1 = fmaf(b1v, w2v[12 + r], sB1);
            sB2 = fmaf(b0, w2v[16 + r], sB2); sB2 = fmaf(b1v, w2v[20 + r], sB2);
        }
        sA0 += __shfl_xor(sA0, 16, 64); sA0 += __shfl_xor(sA0, 32, 64);
        sA1 += __shfl_xor(sA1, 16, 64); sA1 += __shfl_xor(sA1, 32, 64);
        sA2 += __shfl_xor(sA2, 16, 64); sA2 += __shfl_xor(sA2, 32, 64);
        sB0 += __shfl_xor(sB0, 16, 64); sB0 += __shfl_xor(sB0, 32, 64);
        sB1 += __shfl_xor(sB1, 16, 64); sB1 += __shfl_xor(sB1, 32, 64);
        sB2 += __shfl_xor(sB2, 16, 64); sB2 += __shfl_xor(sB2, 32, 64);

        const int r0 = g << 5;
        const int rA = r0 + p, rB = r0 + 16 + p;
        if (lane < 48 && rA < N){
            float val = (q == 0) ? (sA0 + b2v0) : ((q == 1) ? (sA1 + b2v1) : (sA2 + b2v2));
            pt_out[(size_t)rA * 3 + q] = val;
        }
        if (lane < 48 && rB < N){
            float val = (q == 0) ? (sB0 + b2v0) : ((q == 1) ? (sB1 + b2v1) : (sB2 + b2v2));
            pt_out[(size_t)rB * 3 + q] = val;
        }

        vA0 = nA0; vA1 = nA1; vB0 = nB0; vB1 = nB1; rp = np;
    }
}

extern "C" void kernel_launch(void* const* d_in, const int* in_sizes, int n_in,
                              void* d_out, int out_size, void* d_ws, size_t ws_size,
                              hipStream_t stream) {
    const float* feats = (const float*)d_in[0];
    const int*   bidx  = (const int*)d_in[1];
    const float* w1    = (const float*)d_in[2];
    const float* b1    = (const float*)d_in[3];
    const float* gamma = (const float*)d_in[4];
    const float* beta  = (const float*)d_in[5];
    const float* w2    = (const float*)d_in[6];
    const float* b2    = (const float*)d_in[7];
    const float* mw1   = (const float*)d_in[8];
    const float* mb1   = (const float*)d_in[9];
    const float* mw2   = (const float*)d_in[10];
    const float* mb2   = (const float*)d_in[11];
    const float* iw    = (const float*)d_in[12];
    const float* ib    = (const float*)d_in[13];

    const int N = in_sizes[0] / 32;
    const int B = (out_size - 4 * N) / 33;   // out = 3N + N + 32B + B

    float* out    = (float*)d_out;
    float* pt     = out;                       // [N,3]
    float* mask   = out + (size_t)3 * N;       // [N,1]
    float* pooled = out + (size_t)4 * N;       // [B,32]
    float* iou    = pooled + (size_t)B * 32;   // [B,1]

    float* ws      = (float*)d_ws;
    float* ws_sum  = ws;                 // 32
    float* ws_sq   = ws + 32;            // 32
    float* ws_pool = ws + 64;            // B*32

    hipMemsetAsync(ws, 0, (size_t)(64 + B * 32) * sizeof(float), stream);

    pass1_kernel<<<GRID_BLOCKS, TPB, 0, stream>>>(feats, bidx, w1, b1, mw1, mb1, mw2, mb2,
                                                  mask, ws_sum, ws_sq, ws_pool, N, B);
    pass2_kernel<<<GRID_BLOCKS, TPB, 0, stream>>>(feats, bidx, w1, b1, gamma, beta, w2, b2,
                                                  iw, ib, ws_sum, ws_sq, ws_pool,
                                                  pt, pooled, iou, N, B);
}

// Round 3
// 455.321 us; speedup vs baseline: 1.0561x; 1.0561x over previous
//
#include <hip/hip_runtime.h>

#define TPB 256

typedef __attribute__((ext_vector_type(8))) short short8;
typedef __attribute__((ext_vector_type(4))) float floatx4;

__device__ __forceinline__ unsigned short bf_rne(float f){
    union { float f; unsigned u; } c; c.f = f;
    unsigned r = c.u + 0x7fffu + ((c.u >> 16) & 1u);
    return (unsigned short)(r >> 16);
}
// pack trunc-bf16 of (lo,hi) into one dword with a single v_perm_b32
__device__ __forceinline__ unsigned pack_bf(float lo, float hi){
    union { float f; unsigned u; } a, b; a.f = lo; b.f = hi;
    return __builtin_amdgcn_perm(b.u, a.u, 0x07060302u);
}

// ---------------------------------------------------------------------------
// prologue: batch boundaries lb[0..B] by binary search, once for the whole
// launch (R2 post-mortem: the per-block 21-deep dependent-load search chain
// cost ~10-20us/pass).
// ---------------------------------------------------------------------------
__global__ void lb_kernel(const int* __restrict__ bidx, int* __restrict__ ws_lb,
                          int N, int B)
{
    const int t = threadIdx.x;
    if (t <= B){
        int lo = 0, hi = N;
        while (lo < hi){
            const int mid = (lo + hi) >> 1;
            if (bidx[mid] < t) lo = mid + 1; else hi = mid;
        }
        ws_lb[t] = lo;
    }
}

// ---------------------------------------------------------------------------
// R3 core change (both passes): all global feats loads are now FULLY
// COALESCED (lane i reads group_base + i*16B -> 1KB/instruction, 16 fully-
// covered lines -- the m13-copy pattern that hits 6.3TB/s). R0-R2's MFMA-
// layout loads (16B granules strided p*128+q*32, 32 half-covered lines per
// instruction, each line touched by 2 instructions) delivered only ~1.6TB/s
// across every scheduling variant. The (p,q) fragment layout is recovered
// through a wave-private LDS bounce with granule-XOR swizzle:
//   write: lane i (row r=i>>3, granule g=i&7) -> LDS[r][g ^ (r&7)]
//   read : lane(p,q) granule (2q+s)^(p&7) of rows p / 16+p
// Bank-uniform both sides (2 lanes/bank/quarter = free). No barriers: the
// buffer is wave-private and DS ops are wave-in-order.
// ---------------------------------------------------------------------------
__global__ __launch_bounds__(TPB) void pass1_kernel(
    const float* __restrict__ feats, const int* __restrict__ ws_lb,
    const float* __restrict__ w1, const float* __restrict__ b1,
    const float* __restrict__ mw1, const float* __restrict__ mb1,
    const float* __restrict__ mw2, const float* __restrict__ mb2,
    float* __restrict__ mask_out,
    float* __restrict__ ws_sum, float* __restrict__ ws_sq,
    float* __restrict__ ws_pool, int N, int B)
{
    __shared__ float s_stage[TPB/64][1024];   // 4KB per wave
    __shared__ float s_pool[8][32];
    __shared__ float s_sum[32];
    __shared__ float s_sq[32];
    __shared__ int   s_lb[9];

    const int tid  = threadIdx.x;
    const int lane = tid & 63;
    const int wv   = tid >> 6;
    const int p = lane & 15;               // MFMA point col
    const int q = lane >> 4;               // k-group

    if (tid < 32){ s_sum[tid] = 0.f; s_sq[tid] = 0.f; }
    ((float*)s_pool)[tid] = 0.f;
    if (tid <= B) s_lb[tid] = ws_lb[tid];
    __syncthreads();

    short8 aw0, aw1, am0, am1;
    floatx4 ci_h0, ci_h1, ci_m0, ci_m1;
    float mw2v[8];
#pragma unroll
    for (int j = 0; j < 8; ++j){
        const int k = q * 8 + j;
        aw0[j] = (short)bf_rne(w1 [k * 32 + p]);
        aw1[j] = (short)bf_rne(w1 [k * 32 + 16 + p]);
        am0[j] = (short)bf_rne(mw1[k * 32 + p]);
        am1[j] = (short)bf_rne(mw1[k * 32 + 16 + p]);
    }
#pragma unroll
    for (int r = 0; r < 4; ++r){
        const int c0 = q * 4 + r, c1 = 16 + q * 4 + r;
        ci_h0[r] = b1[c0];  ci_h1[r] = b1[c1];
        ci_m0[r] = mb1[c0]; ci_m1[r] = mb1[c1];
        mw2v[r] = mw2[c0];  mw2v[4 + r] = mw2[c1];
    }
    const float mb2s = mb2[0];

    float hsum[8] = {0,0,0,0,0,0,0,0};
    float hsq [8] = {0,0,0,0,0,0,0,0};
    float pacc[4] = {0,0,0,0};

    const int ngroups = (N + 31) >> 5;                   // 32-row groups
    const int nw  = gridDim.x * (TPB / 64);
    const int wid = blockIdx.x * (TPB / 64) + wv;
    const int g0  = (int)((long)wid       * ngroups / nw);
    const int gE  = (int)((long)(wid + 1) * ngroups / nw);

    int curb = 0;
    { const int r = g0 << 5; while (curb < B - 1 && r >= s_lb[curb + 1]) curb++; }
    int lbn = s_lb[curb + 1];

    float* sw = &s_stage[wv][0];
    const int wrow  = lane >> 3;                 // staging row-in-chunk 0..7
    const int wg    = (lane & 7) ^ wrow;         // swizzled write granule
    const int cbase = (lane & 7) << 2;           // pooled channel base
    const int wo0 = ( 0 + wrow) * 32 + (wg << 2);
    const int wo1 = ( 8 + wrow) * 32 + (wg << 2);
    const int wo2 = (16 + wrow) * 32 + (wg << 2);
    const int wo3 = (24 + wrow) * 32 + (wg << 2);
    const int e = p & 7;
    const int ra0 = p * 32        + ((((q << 1)    ) ^ e) << 2);
    const int ra1 = p * 32        + ((((q << 1) + 1) ^ e) << 2);
    const int rb0 = (16 + p) * 32 + ((((q << 1)    ) ^ e) << 2);
    const int rb1 = (16 + p) * 32 + ((((q << 1) + 1) ^ e) << 2);

    // prime group g0
    floatx4 sv0 = {0,0,0,0}, sv1 = {0,0,0,0}, sv2 = {0,0,0,0}, sv3 = {0,0,0,0};
    if (g0 < gE){
        const float* gp = feats + ((size_t)g0 << 10) + (lane << 2);
        const int r = (g0 << 5) + wrow;
        if (r + 24 < N){
            sv0 = *(const floatx4*)(gp);
            sv1 = *(const floatx4*)(gp + 256);
            sv2 = *(const floatx4*)(gp + 512);
            sv3 = *(const floatx4*)(gp + 768);
        } else {
            if (r      < N) sv0 = *(const floatx4*)(gp);
            if (r +  8 < N) sv1 = *(const floatx4*)(gp + 256);
            if (r + 16 < N) sv2 = *(const floatx4*)(gp + 512);
            if (r + 24 < N) sv3 = *(const floatx4*)(gp + 768);
        }
    }

    for (int g = g0; g < gE; ++g){
        // 1. stage current group into wave-private LDS (swizzled, b128)
        *(floatx4*)(sw + wo0) = sv0;
        *(floatx4*)(sw + wo1) = sv1;
        *(floatx4*)(sw + wo2) = sv2;
        *(floatx4*)(sw + wo3) = sv3;

        // 2. prefetch next group (coalesced 1KB/instruction)
        floatx4 nv0 = {0,0,0,0}, nv1 = {0,0,0,0}, nv2 = {0,0,0,0}, nv3 = {0,0,0,0};
        if (g + 1 < gE){
            const float* gp = feats + ((size_t)(g + 1) << 10) + (lane << 2);
            const int r = ((g + 1) << 5) + wrow;
            if (r + 24 < N){
                nv0 = *(const floatx4*)(gp);
                nv1 = *(const floatx4*)(gp + 256);
                nv2 = *(const floatx4*)(gp + 512);
                nv3 = *(const floatx4*)(gp + 768);
            } else {
                if (r      < N) nv0 = *(const floatx4*)(gp);
                if (r +  8 < N) nv1 = *(const floatx4*)(gp + 256);
                if (r + 16 < N) nv2 = *(const floatx4*)(gp + 512);
                if (r + 24 < N) nv3 = *(const floatx4*)(gp + 768);
            }
        }

        // 3. pooled accumulation from the staged registers (lane owns
        //    channels cbase..cbase+3 of rows r0 + {0,8,16,24} + wrow)
        const int r0 = g << 5;
        if (r0 >= lbn){
#pragma unroll
            for (int j = 0; j < 4; ++j){
                if (pacc[j] != 0.f) atomicAdd(&s_pool[curb][cbase + j], pacc[j]);
                pacc[j] = 0.f;
            }
            do { curb++; } while (curb < B - 1 && r0 >= s_lb[curb + 1]);
            lbn = s_lb[curb + 1];
        }
        const bool slow = (r0 + 31 >= lbn) || (r0 + 31 >= N);

        if (!slow){
            pacc[0] += sv0[0] + sv1[0] + sv2[0] + sv3[0];
            pacc[1] += sv0[1] + sv1[1] + sv2[1] + sv3[1];
            pacc[2] += sv0[2] + sv1[2] + sv2[2] + sv3[2];
            pacc[3] += sv0[3] + sv1[3] + sv2[3] + sv3[3];
        } else {
#define SLOWROW(SV, L) { \
            const int row = r0 + (L * 8) + wrow; \
            if (row < N){ \
                int bl = curb; \
                for (int c = curb + 1; c < B; ++c) bl += (row >= s_lb[c]); \
                atomicAdd(&s_pool[bl][cbase + 0], SV[0]); \
                atomicAdd(&s_pool[bl][cbase + 1], SV[1]); \
                atomicAdd(&s_pool[bl][cbase + 2], SV[2]); \
                atomicAdd(&s_pool[bl][cbase + 3], SV[3]); \
            } }
            SLOWROW(sv0, 0) SLOWROW(sv1, 1) SLOWROW(sv2, 2) SLOWROW(sv3, 3)
#undef SLOWROW
        }

        // 4. MFMA fragments back from LDS (swizzled read, bank-uniform)
        const floatx4 vA0 = *(const floatx4*)(sw + ra0);
        const floatx4 vA1 = *(const floatx4*)(sw + ra1);
        const floatx4 vB0 = *(const floatx4*)(sw + rb0);
        const floatx4 vB1 = *(const floatx4*)(sw + rb1);

        short8 bfA, bfB;
        {
            unsigned* ba = (unsigned*)&bfA;
            ba[0] = pack_bf(vA0[0], vA0[1]); ba[1] = pack_bf(vA0[2], vA0[3]);
            ba[2] = pack_bf(vA1[0], vA1[1]); ba[3] = pack_bf(vA1[2], vA1[3]);
            unsigned* bb = (unsigned*)&bfB;
            bb[0] = pack_bf(vB0[0], vB0[1]); bb[1] = pack_bf(vB0[2], vB0[3]);
            bb[2] = pack_bf(vB1[0], vB1[1]); bb[3] = pack_bf(vB1[2], vB1[3]);
        }

        const floatx4 chA0 = __builtin_amdgcn_mfma_f32_16x16x32_bf16(aw0, bfA, ci_h0, 0, 0, 0);
        const floatx4 chA1 = __builtin_amdgcn_mfma_f32_16x16x32_bf16(aw1, bfA, ci_h1, 0, 0, 0);
        const floatx4 cmA0 = __builtin_amdgcn_mfma_f32_16x16x32_bf16(am0, bfA, ci_m0, 0, 0, 0);
        const floatx4 cmA1 = __builtin_amdgcn_mfma_f32_16x16x32_bf16(am1, bfA, ci_m1, 0, 0, 0);
        const floatx4 chB0 = __builtin_amdgcn_mfma_f32_16x16x32_bf16(aw0, bfB, ci_h0, 0, 0, 0);
        const floatx4 chB1 = __builtin_amdgcn_mfma_f32_16x16x32_bf16(aw1, bfB, ci_h1, 0, 0, 0);
        const floatx4 cmB0 = __builtin_amdgcn_mfma_f32_16x16x32_bf16(am0, bfB, ci_m0, 0, 0, 0);
        const floatx4 cmB1 = __builtin_amdgcn_mfma_f32_16x16x32_bf16(am1, bfB, ci_m1, 0, 0, 0);

        if (r0 + 31 < N){
#pragma unroll
            for (int r = 0; r < 4; ++r){
                const float a0 = chA0[r], b0 = chB0[r];
                hsum[r] += a0 + b0;
                hsq [r] = fmaf(a0, a0, fmaf(b0, b0, hsq[r]));
                const float a1 = chA1[r], b1v = chB1[r];
                hsum[4 + r] += a1 + b1v;
                hsq [4 + r] = fmaf(a1, a1, fmaf(b1v, b1v, hsq[4 + r]));
            }
        } else {
            if (r0 + p < N){
#pragma unroll
                for (int r = 0; r < 4; ++r){
                    const float a0 = chA0[r]; hsum[r]     += a0; hsq[r]     = fmaf(a0, a0, hsq[r]);
                    const float a1 = chA1[r]; hsum[4 + r] += a1; hsq[4 + r] = fmaf(a1, a1, hsq[4 + r]);
                }
            }
            if (r0 + 16 + p < N){
#pragma unroll
                for (int r = 0; r < 4; ++r){
                    const float b0 = chB0[r]; hsum[r]     += b0; hsq[r]     = fmaf(b0, b0, hsq[r]);
                    const float b1v = chB1[r]; hsum[4 + r] += b1v; hsq[4 + r] = fmaf(b1v, b1v, hsq[4 + r]);
                }
            }
        }

        float tmA = 0.f, tmB = 0.f;
#pragma unroll
        for (int r = 0; r < 4; ++r){
            tmA = fmaf(fmaxf(cmA0[r], 0.f), mw2v[r],     tmA);
            tmA = fmaf(fmaxf(cmA1[r], 0.f), mw2v[4 + r], tmA);
            tmB = fmaf(fmaxf(cmB0[r], 0.f), mw2v[r],     tmB);
            tmB = fmaf(fmaxf(cmB1[r], 0.f), mw2v[4 + r], tmB);
        }
        tmA += __shfl_xor(tmA, 16, 64); tmA += __shfl_xor(tmA, 32, 64);
        tmB += __shfl_xor(tmB, 16, 64); tmB += __shfl_xor(tmB, 32, 64);
        if (q == 0 && (r0 + p) < N)      mask_out[r0 + p]      = tmA + mb2s;
        if (q == 0 && (r0 + 16 + p) < N) mask_out[r0 + 16 + p] = tmB + mb2s;

        sv0 = nv0; sv1 = nv1; sv2 = nv2; sv3 = nv3;
    }

    // final flush
#pragma unroll
    for (int j = 0; j < 4; ++j){
        if (pacc[j] != 0.f) atomicAdd(&s_pool[curb][cbase + j], pacc[j]);
    }
#pragma unroll
    for (int i = 0; i < 8; ++i){
        const int ch = (i >> 2) * 16 + q * 4 + (i & 3);
        atomicAdd(&s_sum[ch], hsum[i]);
        atomicAdd(&s_sq[ch],  hsq[i]);
    }
    __syncthreads();
    if (tid < 32){
        atomicAdd(&ws_sum[tid], s_sum[tid]);
        atomicAdd(&ws_sq[tid],  s_sq[tid]);
    }
    {
        const float pv = ((float*)s_pool)[tid];
        if (pv != 0.f) atomicAdd(&ws_pool[tid], pv);   // chunked -> mostly zero
    }
}

// ---------------------------------------------------------------------------
// pass2: BN fold from global stats; block 0 writes pooled+iou; folded-weight
// MFMA, relu, 32x3 projection. Same coalesced-load + LDS-bounce as pass1.
// ---------------------------------------------------------------------------
__global__ __launch_bounds__(TPB) void pass2_kernel(
    const float* __restrict__ feats, const int* __restrict__ ws_lb,
    const float* __restrict__ w1, const float* __restrict__ b1,
    const float* __restrict__ gamma, const float* __restrict__ beta,
    const float* __restrict__ w2, const float* __restrict__ b2,
    const float* __restrict__ iw, const float* __restrict__ ib,
    const float* __restrict__ ws_sum, const float* __restrict__ ws_sq,
    const float* __restrict__ ws_pool,
    float* __restrict__ pt_out, float* __restrict__ pooled_out,
    float* __restrict__ iou_out, int N, int B)
{
    __shared__ float s_stage[TPB/64][1024];
    __shared__ float s_sc[32];
    __shared__ float s_bp[32];
    __shared__ float s_pooled[256];
    __shared__ int   s_lb[9];

    const int tid  = threadIdx.x;
    const int lane = tid & 63;
    const int wv   = tid >> 6;
    const int p = lane & 15;
    const int q = lane >> 4;

    if (tid < 32){
        const float invN = 1.f / (float)N;
        const float mu  = ws_sum[tid] * invN;
        const float var = ws_sq[tid] * invN - mu * mu;
        const float s   = gamma[tid] * rsqrtf(var + 1e-4f);
        s_sc[tid] = s;
        s_bp[tid] = (b1[tid] - mu) * s + beta[tid];
    }
    if (tid <= B) s_lb[tid] = ws_lb[tid];
    __syncthreads();

    if (blockIdx.x == 0){
        if (tid < B * 32){
            const int bb = tid >> 5;
            const float cnt = fmaxf((float)(s_lb[bb + 1] - s_lb[bb]), 1.f);
            const float pv = ws_pool[tid] / cnt;
            s_pooled[tid]   = pv;
            pooled_out[tid] = pv;
        }
        __syncthreads();
        if (tid < B){
            float acc = ib[0];
#pragma unroll
            for (int i = 0; i < 32; ++i) acc = fmaf(s_pooled[tid * 32 + i], iw[i], acc);
            iou_out[tid] = acc;
        }
    }

    short8 pw0, pw1;
    floatx4 pc0, pc1;
    float w2v[24];
    const float sc0 = s_sc[p], sc1 = s_sc[16 + p];
#pragma unroll
    for (int j = 0; j < 8; ++j){
        const int k = q * 8 + j;
        pw0[j] = (short)bf_rne(w1[k * 32 + p]      * sc0);
        pw1[j] = (short)bf_rne(w1[k * 32 + 16 + p] * sc1);
    }
#pragma unroll
    for (int r = 0; r < 4; ++r){
        pc0[r] = s_bp[q * 4 + r];
        pc1[r] = s_bp[16 + q * 4 + r];
    }
#pragma unroll
    for (int i = 0; i < 8; ++i){
        const int ch = (i >> 2) * 16 + q * 4 + (i & 3);
        w2v[i]      = w2[ch * 3 + 0];
        w2v[8 + i]  = w2[ch * 3 + 1];
        w2v[16 + i] = w2[ch * 3 + 2];
    }
    const float b2v0 = b2[0], b2v1 = b2[1], b2v2 = b2[2];

    const int ngroups = (N + 31) >> 5;
    const int nw  = gridDim.x * (TPB / 64);
    const int wid = blockIdx.x * (TPB / 64) + wv;
    const int g0  = (int)((long)wid       * ngroups / nw);
    const int gE  = (int)((long)(wid + 1) * ngroups / nw);

    float* sw = &s_stage[wv][0];
    const int wrow = lane >> 3;
    const int wg   = (lane & 7) ^ wrow;
    const int wo0 = ( 0 + wrow) * 32 + (wg << 2);
    const int wo1 = ( 8 + wrow) * 32 + (wg << 2);
    const int wo2 = (16 + wrow) * 32 + (wg << 2);
    const int wo3 = (24 + wrow) * 32 + (wg << 2);
    const int e = p & 7;
    const int ra0 = p * 32        + ((((q << 1)    ) ^ e) << 2);
    const int ra1 = p * 32        + ((((q << 1) + 1) ^ e) << 2);
    const int rb0 = (16 + p) * 32 + ((((q << 1)    ) ^ e) << 2);
    const int rb1 = (16 + p) * 32 + ((((q << 1) + 1) ^ e) << 2);

    floatx4 sv0 = {0,0,0,0}, sv1 = {0,0,0,0}, sv2 = {0,0,0,0}, sv3 = {0,0,0,0};
    if (g0 < gE){
        const float* gp = feats + ((size_t)g0 << 10) + (lane << 2);
        const int r = (g0 << 5) + wrow;
        if (r + 24 < N){
            sv0 = *(const floatx4*)(gp);
            sv1 = *(const floatx4*)(gp + 256);
            sv2 = *(const floatx4*)(gp + 512);
            sv3 = *(const floatx4*)(gp + 768);
        } else {
            if (r      < N) sv0 = *(const floatx4*)(gp);
            if (r +  8 < N) sv1 = *(const floatx4*)(gp + 256);
            if (r + 16 < N) sv2 = *(const floatx4*)(gp + 512);
            if (r + 24 < N) sv3 = *(const floatx4*)(gp + 768);
        }
    }

    for (int g = g0; g < gE; ++g){
        *(floatx4*)(sw + wo0) = sv0;
        *(floatx4*)(sw + wo1) = sv1;
        *(floatx4*)(sw + wo2) = sv2;
        *(floatx4*)(sw + wo3) = sv3;

        floatx4 nv0 = {0,0,0,0}, nv1 = {0,0,0,0}, nv2 = {0,0,0,0}, nv3 = {0,0,0,0};
        if (g + 1 < gE){
            const float* gp = feats + ((size_t)(g + 1) << 10) + (lane << 2);
            const int r = ((g + 1) << 5) + wrow;
            if (r + 24 < N){
                nv0 = *(const floatx4*)(gp);
                nv1 = *(const floatx4*)(gp + 256);
                nv2 = *(const floatx4*)(gp + 512);
                nv3 = *(const floatx4*)(gp + 768);
            } else {
                if (r      < N) nv0 = *(const floatx4*)(gp);
                if (r +  8 < N) nv1 = *(const floatx4*)(gp + 256);
                if (r + 16 < N) nv2 = *(const floatx4*)(gp + 512);
                if (r + 24 < N) nv3 = *(const floatx4*)(gp + 768);
            }
        }

        const floatx4 vA0 = *(const floatx4*)(sw + ra0);
        const floatx4 vA1 = *(const floatx4*)(sw + ra1);
        const floatx4 vB0 = *(const floatx4*)(sw + rb0);
        const floatx4 vB1 = *(const floatx4*)(sw + rb1);

        short8 bfA, bfB;
        {
            unsigned* ba = (unsigned*)&bfA;
            ba[0] = pack_bf(vA0[0], vA0[1]); ba[1] = pack_bf(vA0[2], vA0[3]);
            ba[2] = pack_bf(vA1[0], vA1[1]); ba[3] = pack_bf(vA1[2], vA1[3]);
            unsigned* bb = (unsigned*)&bfB;
            bb[0] = pack_bf(vB0[0], vB0[1]); bb[1] = pack_bf(vB0[2], vB0[3]);
            bb[2] = pack_bf(vB1[0], vB1[1]); bb[3] = pack_bf(vB1[2], vB1[3]);
        }

        const floatx4 cA0 = __builtin_amdgcn_mfma_f32_16x16x32_bf16(pw0, bfA, pc0, 0, 0, 0);
        const floatx4 cA1 = __builtin_amdgcn_mfma_f32_16x16x32_bf16(pw1, bfA, pc1, 0, 0, 0);
        const floatx4 cB0 = __builtin_amdgcn_mfma_f32_16x16x32_bf16(pw0, bfB, pc0, 0, 0, 0);
        const floatx4 cB1 = __builtin_amdgcn_mfma_f32_16x16x32_bf16(pw1, bfB, pc1, 0, 0, 0);

        float sA0 = 0.f, sA1 = 0.f, sA2 = 0.f, sB0 = 0.f, sB1 = 0.f, sB2 = 0.f;
#pragma unroll
        for (int r = 0; r < 4; ++r){
            const float a0 = fmaxf(cA0[r], 0.f);
            const float a1 = fmaxf(cA1[r], 0.f);
            sA0 = fmaf(a0, w2v[r],      sA0); sA0 = fmaf(a1, w2v[4 + r],  sA0);
            sA1 = fmaf(a0, w2v[8 + r],  sA1); sA1 = fmaf(a1, w2v[12 + r], sA1);
            sA2 = fmaf(a0, w2v[16 + r], sA2); sA2 = fmaf(a1, w2v[20 + r], sA2);
            const float b0 = fmaxf(cB0[r], 0.f);
            const float b1v = fmaxf(cB1[r], 0.f);
            sB0 = fmaf(b0, w2v[r],      sB0); sB0 = fmaf(b1v, w2v[4 + r],  sB0);
            sB1 = fmaf(b0, w2v[8 + r],  sB1); sB1 = fmaf(b1v, w2v[12 + r], sB1);
            sB2 = fmaf(b0, w2v[16 + r], sB2); sB2 = fmaf(b1v, w2v[20 + r], sB2);
        }
        sA0 += __shfl_xor(sA0, 16, 64); sA0 += __shfl_xor(sA0, 32, 64);
        sA1 += __shfl_xor(sA1, 16, 64); sA1 += __shfl_xor(sA1, 32, 64);
        sA2 += __shfl_xor(sA2, 16, 64); sA2 += __shfl_xor(sA2, 32, 64);
        sB0 += __shfl_xor(sB0, 16, 64); sB0 += __shfl_xor(sB0, 32, 64);
        sB1 += __shfl_xor(sB1, 16, 64); sB1 += __shfl_xor(sB1, 32, 64);
        sB2 += __shfl_xor(sB2, 16, 64); sB2 += __shfl_xor(sB2, 32, 64);

        const int r0 = g << 5;
        const int rA = r0 + p, rB = r0 + 16 + p;
        if (lane < 48 && rA < N){
            float val = (q == 0) ? (sA0 + b2v0) : ((q == 1) ? (sA1 + b2v1) : (sA2 + b2v2));
            pt_out[(size_t)rA * 3 + q] = val;
        }
        if (lane < 48 && rB < N){
            float val = (q == 0) ? (sB0 + b2v0) : ((q == 1) ? (sB1 + b2v1) : (sB2 + b2v2));
            pt_out[(size_t)rB * 3 + q] = val;
        }

        sv0 = nv0; sv1 = nv1; sv2 = nv2; sv3 = nv3;
    }
}

extern "C" void kernel_launch(void* const* d_in, const int* in_sizes, int n_in,
                              void* d_out, int out_size, void* d_ws, size_t ws_size,
                              hipStream_t stream) {
    const float* feats = (const float*)d_in[0];
    const int*   bidx  = (const int*)d_in[1];
    const float* w1    = (const float*)d_in[2];
    const float* b1    = (const float*)d_in[3];
    const float* gamma = (const float*)d_in[4];
    const float* beta  = (const float*)d_in[5];
    const float* w2    = (const float*)d_in[6];
    const float* b2    = (const float*)d_in[7];
    const float* mw1   = (const float*)d_in[8];
    const float* mb1   = (const float*)d_in[9];
    const float* mw2   = (const float*)d_in[10];
    const float* mb2   = (const float*)d_in[11];
    const float* iw    = (const float*)d_in[12];
    const float* ib    = (const float*)d_in[13];

    const int N = in_sizes[0] / 32;
    const int B = (out_size - 4 * N) / 33;   // out = 3N + N + 32B + B

    float* out    = (float*)d_out;
    float* pt     = out;                       // [N,3]
    float* mask   = out + (size_t)3 * N;       // [N,1]
    float* pooled = out + (size_t)4 * N;       // [B,32]
    float* iou    = pooled + (size_t)B * 32;   // [B,1]

    float* ws      = (float*)d_ws;
    float* ws_sum  = ws;                        // 32
    float* ws_sq   = ws + 32;                   // 32
    float* ws_pool = ws + 64;                   // B*32
    int*   ws_lb   = (int*)(ws + 64 + (size_t)B * 32);  // B+1 ints

    hipMemsetAsync(ws, 0, (size_t)(64 + B * 32) * sizeof(float), stream);

    int dev = 0;
    hipGetDevice(&dev);
    hipDeviceProp_t prop;
    hipGetDeviceProperties(&prop, dev);
    int per1 = 0, per2 = 0;
    hipOccupancyMaxActiveBlocksPerMultiprocessor(&per1, pass1_kernel, TPB, 0);
    hipOccupancyMaxActiveBlocksPerMultiprocessor(&per2, pass2_kernel, TPB, 0);
    int g1 = per1 * prop.multiProcessorCount; if (g1 < 512) g1 = 512;
    int g2 = per2 * prop.multiProcessorCount; if (g2 < 512) g2 = 512;

    lb_kernel<<<1, 64, 0, stream>>>(bidx, ws_lb, N, B);
    pass1_kernel<<<g1, TPB, 0, stream>>>(feats, ws_lb, w1, b1, mw1, mb1, mw2, mb2,
                                         mask, ws_sum, ws_sq, ws_pool, N, B);
    pass2_kernel<<<g2, TPB, 0, stream>>>(feats, ws_lb, w1, b1, gamma, beta, w2, b2,
                                         iw, ib, ws_sum, ws_sq, ws_pool,
                                         pt, pooled, iou, N, B);
}

// Round 4
// 453.313 us; speedup vs baseline: 1.0608x; 1.0044x over previous
//
#include <hip/hip_runtime.h>

#define TPB 256
#define GRID_BLOCKS 768

typedef __attribute__((ext_vector_type(8))) short short8;
typedef __attribute__((ext_vector_type(4))) float floatx4;

typedef __attribute__((address_space(3))) unsigned lds_u32;
typedef const __attribute__((address_space(1))) unsigned glb_u32;

__device__ __forceinline__ unsigned short bf_rne(float f){
    union { float f; unsigned u; } c; c.f = f;
    unsigned r = c.u + 0x7fffu + ((c.u >> 16) & 1u);
    return (unsigned short)(r >> 16);
}
__device__ __forceinline__ unsigned pack_bf(float lo, float hi){
    union { float f; unsigned u; } a, b; a.f = lo; b.f = hi;
    return __builtin_amdgcn_perm(b.u, a.u, 0x07060302u);
}
// async DMA global->LDS, 16B/lane: lds dest = (uniform) l + lane*16,
// global src = per-lane pointer g.
__device__ __forceinline__ void gload16(const float* g, float* l){
    __builtin_amdgcn_global_load_lds((glb_u32*)g, (lds_u32*)l, 16, 0, 0);
}

#define VMWAIT(n) asm volatile("s_waitcnt vmcnt(" #n ")" ::: "memory")

// ---------------------------------------------------------------------------
// prologue: batch boundaries lb[0..B] once.
// ---------------------------------------------------------------------------
__global__ void lb_kernel(const int* __restrict__ bidx, int* __restrict__ ws_lb,
                          int N, int B)
{
    const int t = threadIdx.x;
    if (t <= B){
        int lo = 0, hi = N;
        while (lo < hi){
            const int mid = (lo + hi) >> 1;
            if (bidx[mid] < t) lo = mid + 1; else hi = mid;
        }
        ws_lb[t] = lo;
    }
}

// ---------------------------------------------------------------------------
// R4: staging via __builtin_amdgcn_global_load_lds (width 16), wave-private
// 3-buffer pipeline, depth-2 prefetch, counted vmcnt waits (never 0 in
// steady state). R1-R3 post-mortem: every reg-prefetch structure pinned at
// ~2.8 B/cy/CU (1.7 TB/s) with all pipes idle -- the VGPR-return staging
// path is the invariant bottleneck; DMA-to-LDS is the documented fix.
// Swizzle is folded into the GLOBAL source address (granule-XOR within each
// 128B row -> coalescing preserved, LDS dest linear as HW requires):
//   chunk k, lane i: src row = g*32 + k*8 + (i>>3), granule (i&7)^((i>>3)&7)
//   => LDS slot s of row r holds global granule s^(r&7)  (same as R3, which
//      passed bit-exact). Fragment reads and pool readback unchanged math.
// vmcnt accounting (in-order decrement): ops issued after group g's 4 loads
// = stores(g-2)<=2 + loads(g+1) 4 + stores(g-1)<=2 + loads(g+2) 4 = 12.
// ---------------------------------------------------------------------------
__global__ __launch_bounds__(TPB) void pass1_kernel(
    const float* __restrict__ feats, const int* __restrict__ ws_lb,
    const float* __restrict__ w1, const float* __restrict__ b1,
    const float* __restrict__ mw1, const float* __restrict__ mb1,
    const float* __restrict__ mw2, const float* __restrict__ mb2,
    float* __restrict__ mask_out,
    float* __restrict__ ws_sum, float* __restrict__ ws_sq,
    float* __restrict__ ws_pool, int N, int B)
{
    __shared__ float s_stage[TPB/64][3072];   // 3 x 4KB per wave
    __shared__ float s_pool[8][32];
    __shared__ float s_sum[32];
    __shared__ float s_sq[32];
    __shared__ int   s_lb[9];

    const int tid  = threadIdx.x;
    const int lane = tid & 63;
    const int wv   = tid >> 6;
    const int p = lane & 15;               // MFMA point col
    const int q = lane >> 4;               // k-group

    if (tid < 32){ s_sum[tid] = 0.f; s_sq[tid] = 0.f; }
    ((float*)s_pool)[tid] = 0.f;
    if (tid <= B) s_lb[tid] = ws_lb[tid];
    __syncthreads();

    short8 aw0, aw1, am0, am1;
    floatx4 ci_h0, ci_h1, ci_m0, ci_m1;
    float mw2v[8];
#pragma unroll
    for (int j = 0; j < 8; ++j){
        const int k = q * 8 + j;
        aw0[j] = (short)bf_rne(w1 [k * 32 + p]);
        aw1[j] = (short)bf_rne(w1 [k * 32 + 16 + p]);
        am0[j] = (short)bf_rne(mw1[k * 32 + p]);
        am1[j] = (short)bf_rne(mw1[k * 32 + 16 + p]);
    }
#pragma unroll
    for (int r = 0; r < 4; ++r){
        const int c0 = q * 4 + r, c1 = 16 + q * 4 + r;
        ci_h0[r] = b1[c0];  ci_h1[r] = b1[c1];
        ci_m0[r] = mb1[c0]; ci_m1[r] = mb1[c1];
        mw2v[r] = mw2[c0];  mw2v[4 + r] = mw2[c1];
    }
    const float mb2s = mb2[0];

    float hsum[8] = {0,0,0,0,0,0,0,0};
    float hsq [8] = {0,0,0,0,0,0,0,0};
    float pacc[4] = {0,0,0,0};

    const int ngroups = (N + 31) >> 5;                   // 32-row groups
    const int nw  = gridDim.x * (TPB / 64);
    const int wid = blockIdx.x * (TPB / 64) + wv;
    const int g0  = (int)((long)wid       * ngroups / nw);
    const int gE  = (int)((long)(wid + 1) * ngroups / nw);

    int curb = 0;
    { const int r = g0 << 5; while (curb < B - 1 && r >= s_lb[curb + 1]) curb++; }
    int lbn = s_lb[curb + 1];

    float* sw = &s_stage[wv][0];
    const int wrow = lane >> 3;                       // LDS row-in-chunk 0..7
    const int gofs = ((lane & 7) ^ wrow) << 2;        // swizzled granule (floats)
    const int cbase = gofs;                           // pooled channel base = 4*granule
    const int Nm1 = N - 1;
    const int e = p & 7;
    const int ra0 = p * 32        + ((((q << 1)    ) ^ e) << 2);
    const int ra1 = p * 32        + ((((q << 1) + 1) ^ e) << 2);
    const int rb0 = (16 + p) * 32 + ((((q << 1)    ) ^ e) << 2);
    const int rb1 = (16 + p) * 32 + ((((q << 1) + 1) ^ e) << 2);

#define ISSUE_GROUP(J) { \
    float* lb_ = sw + ((J) % 3) * 1024; \
    const int rbase_ = (J) << 5; \
    _Pragma("unroll") \
    for (int k_ = 0; k_ < 4; ++k_){ \
        int row_ = rbase_ + (k_ << 3) + wrow; \
        row_ = row_ < Nm1 ? row_ : Nm1; \
        gload16(feats + ((size_t)row_ << 5) + gofs, lb_ + (k_ << 8)); \
    } }

    int issued = g0;
    if (issued < gE)          { ISSUE_GROUP(issued); ++issued; }
    if (issued < gE && issued < g0 + 2){ ISSUE_GROUP(issued); ++issued; }

    for (int g = g0; g < gE; ++g){
        if (issued < gE){ ISSUE_GROUP(issued); ++issued; }
        const int ahead = issued - g - 1;
        if (ahead >= 2)      { VMWAIT(12); }
        else if (ahead == 1) { VMWAIT(8); }
        else                 { VMWAIT(0); }
        __builtin_amdgcn_sched_barrier(0);

        const float* cb = sw + (g % 3) * 1024;
        const int r0 = g << 5;

        // pool values: linear readback of lane's own staged 16B per chunk
        const floatx4 pv0 = *(const floatx4*)(cb + (lane << 2));
        const floatx4 pv1 = *(const floatx4*)(cb + 256 + (lane << 2));
        const floatx4 pv2 = *(const floatx4*)(cb + 512 + (lane << 2));
        const floatx4 pv3 = *(const floatx4*)(cb + 768 + (lane << 2));

        if (r0 >= lbn){
#pragma unroll
            for (int j = 0; j < 4; ++j){
                if (pacc[j] != 0.f) atomicAdd(&s_pool[curb][cbase + j], pacc[j]);
                pacc[j] = 0.f;
            }
            do { curb++; } while (curb < B - 1 && r0 >= s_lb[curb + 1]);
            lbn = s_lb[curb + 1];
        }
        const bool slow = (r0 + 31 >= lbn) || (r0 + 31 >= N);

        if (!slow){
            pacc[0] += pv0[0] + pv1[0] + pv2[0] + pv3[0];
            pacc[1] += pv0[1] + pv1[1] + pv2[1] + pv3[1];
            pacc[2] += pv0[2] + pv1[2] + pv2[2] + pv3[2];
            pacc[3] += pv0[3] + pv1[3] + pv2[3] + pv3[3];
        } else {
#define SLOWROW(SV, L) { \
            const int row = r0 + (L * 8) + wrow; \
            if (row < N){ \
                int bl = curb; \
                for (int c = curb + 1; c < B; ++c) bl += (row >= s_lb[c]); \
                atomicAdd(&s_pool[bl][cbase + 0], SV[0]); \
                atomicAdd(&s_pool[bl][cbase + 1], SV[1]); \
                atomicAdd(&s_pool[bl][cbase + 2], SV[2]); \
                atomicAdd(&s_pool[bl][cbase + 3], SV[3]); \
            } }
            SLOWROW(pv0, 0) SLOWROW(pv1, 1) SLOWROW(pv2, 2) SLOWROW(pv3, 3)
#undef SLOWROW
        }

        // MFMA fragments (swizzled read, bank-uniform; same math as R3)
        const floatx4 vA0 = *(const floatx4*)(cb + ra0);
        const floatx4 vA1 = *(const floatx4*)(cb + ra1);
        const floatx4 vB0 = *(const floatx4*)(cb + rb0);
        const floatx4 vB1 = *(const floatx4*)(cb + rb1);

        short8 bfA, bfB;
        {
            unsigned* ba = (unsigned*)&bfA;
            ba[0] = pack_bf(vA0[0], vA0[1]); ba[1] = pack_bf(vA0[2], vA0[3]);
            ba[2] = pack_bf(vA1[0], vA1[1]); ba[3] = pack_bf(vA1[2], vA1[3]);
            unsigned* bb = (unsigned*)&bfB;
            bb[0] = pack_bf(vB0[0], vB0[1]); bb[1] = pack_bf(vB0[2], vB0[3]);
            bb[2] = pack_bf(vB1[0], vB1[1]); bb[3] = pack_bf(vB1[2], vB1[3]);
        }

        const floatx4 chA0 = __builtin_amdgcn_mfma_f32_16x16x32_bf16(aw0, bfA, ci_h0, 0, 0, 0);
        const floatx4 chA1 = __builtin_amdgcn_mfma_f32_16x16x32_bf16(aw1, bfA, ci_h1, 0, 0, 0);
        const floatx4 cmA0 = __builtin_amdgcn_mfma_f32_16x16x32_bf16(am0, bfA, ci_m0, 0, 0, 0);
        const floatx4 cmA1 = __builtin_amdgcn_mfma_f32_16x16x32_bf16(am1, bfA, ci_m1, 0, 0, 0);
        const floatx4 chB0 = __builtin_amdgcn_mfma_f32_16x16x32_bf16(aw0, bfB, ci_h0, 0, 0, 0);
        const floatx4 chB1 = __builtin_amdgcn_mfma_f32_16x16x32_bf16(aw1, bfB, ci_h1, 0, 0, 0);
        const floatx4 cmB0 = __builtin_amdgcn_mfma_f32_16x16x32_bf16(am0, bfB, ci_m0, 0, 0, 0);
        const floatx4 cmB1 = __builtin_amdgcn_mfma_f32_16x16x32_bf16(am1, bfB, ci_m1, 0, 0, 0);

        if (r0 + 31 < N){
#pragma unroll
            for (int r = 0; r < 4; ++r){
                const float a0 = chA0[r], b0 = chB0[r];
                hsum[r] += a0 + b0;
                hsq [r] = fmaf(a0, a0, fmaf(b0, b0, hsq[r]));
                const float a1 = chA1[r], b1v = chB1[r];
                hsum[4 + r] += a1 + b1v;
                hsq [4 + r] = fmaf(a1, a1, fmaf(b1v, b1v, hsq[4 + r]));
            }
        } else {
            if (r0 + p < N){
#pragma unroll
                for (int r = 0; r < 4; ++r){
                    const float a0 = chA0[r]; hsum[r]     += a0; hsq[r]     = fmaf(a0, a0, hsq[r]);
                    const float a1 = chA1[r]; hsum[4 + r] += a1; hsq[4 + r] = fmaf(a1, a1, hsq[4 + r]);
                }
            }
            if (r0 + 16 + p < N){
#pragma unroll
                for (int r = 0; r < 4; ++r){
                    const float b0 = chB0[r]; hsum[r]     += b0; hsq[r]     = fmaf(b0, b0, hsq[r]);
                    const float b1v = chB1[r]; hsum[4 + r] += b1v; hsq[4 + r] = fmaf(b1v, b1v, hsq[4 + r]);
                }
            }
        }

        float tmA = 0.f, tmB = 0.f;
#pragma unroll
        for (int r = 0; r < 4; ++r){
            tmA = fmaf(fmaxf(cmA0[r], 0.f), mw2v[r],     tmA);
            tmA = fmaf(fmaxf(cmA1[r], 0.f), mw2v[4 + r], tmA);
            tmB = fmaf(fmaxf(cmB0[r], 0.f), mw2v[r],     tmB);
            tmB = fmaf(fmaxf(cmB1[r], 0.f), mw2v[4 + r], tmB);
        }
        tmA += __shfl_xor(tmA, 16, 64); tmA += __shfl_xor(tmA, 32, 64);
        tmB += __shfl_xor(tmB, 16, 64); tmB += __shfl_xor(tmB, 32, 64);
        if (q == 0 && (r0 + p) < N)      mask_out[r0 + p]      = tmA + mb2s;
        if (q == 0 && (r0 + 16 + p) < N) mask_out[r0 + 16 + p] = tmB + mb2s;
    }

    // final flush
#pragma unroll
    for (int j = 0; j < 4; ++j){
        if (pacc[j] != 0.f) atomicAdd(&s_pool[curb][cbase + j], pacc[j]);
    }
#pragma unroll
    for (int i = 0; i < 8; ++i){
        const int ch = (i >> 2) * 16 + q * 4 + (i & 3);
        atomicAdd(&s_sum[ch], hsum[i]);
        atomicAdd(&s_sq[ch],  hsq[i]);
    }
    __syncthreads();
    if (tid < 32){
        atomicAdd(&ws_sum[tid], s_sum[tid]);
        atomicAdd(&ws_sq[tid],  s_sq[tid]);
    }
    {
        const float pv = ((float*)s_pool)[tid];
        if (pv != 0.f) atomicAdd(&ws_pool[tid], pv);   // chunked -> mostly zero
    }
#undef ISSUE_GROUP
}

// ---------------------------------------------------------------------------
// pass2: BN fold from global stats; block 0 writes pooled+iou; folded-weight
// MFMA, relu, 32x3 projection. Same DMA pipeline as pass1 (no pool).
// ---------------------------------------------------------------------------
__global__ __launch_bounds__(TPB) void pass2_kernel(
    const float* __restrict__ feats, const int* __restrict__ ws_lb,
    const float* __restrict__ w1, const float* __restrict__ b1,
    const float* __restrict__ gamma, const float* __restrict__ beta,
    const float* __restrict__ w2, const float* __restrict__ b2,
    const float* __restrict__ iw, const float* __restrict__ ib,
    const float* __restrict__ ws_sum, const float* __restrict__ ws_sq,
    const float* __restrict__ ws_pool,
    float* __restrict__ pt_out, float* __restrict__ pooled_out,
    float* __restrict__ iou_out, int N, int B)
{
    __shared__ float s_stage[TPB/64][3072];
    __shared__ float s_sc[32];
    __shared__ float s_bp[32];
    __shared__ float s_pooled[256];
    __shared__ int   s_lb[9];

    const int tid  = threadIdx.x;
    const int lane = tid & 63;
    const int wv   = tid >> 6;
    const int p = lane & 15;
    const int q = lane >> 4;

    if (tid < 32){
        const float invN = 1.f / (float)N;
        const float mu  = ws_sum[tid] * invN;
        const float var = ws_sq[tid] * invN - mu * mu;
        const float s   = gamma[tid] * rsqrtf(var + 1e-4f);
        s_sc[tid] = s;
        s_bp[tid] = (b1[tid] - mu) * s + beta[tid];
    }
    if (tid <= B) s_lb[tid] = ws_lb[tid];
    __syncthreads();

    if (blockIdx.x == 0){
        if (tid < B * 32){
            const int bb = tid >> 5;
            const float cnt = fmaxf((float)(s_lb[bb + 1] - s_lb[bb]), 1.f);
            const float pv = ws_pool[tid] / cnt;
            s_pooled[tid]   = pv;
            pooled_out[tid] = pv;
        }
        __syncthreads();
        if (tid < B){
            float acc = ib[0];
#pragma unroll
            for (int i = 0; i < 32; ++i) acc = fmaf(s_pooled[tid * 32 + i], iw[i], acc);
            iou_out[tid] = acc;
        }
    }

    short8 pw0, pw1;
    floatx4 pc0, pc1;
    float w2v[24];
    const float sc0 = s_sc[p], sc1 = s_sc[16 + p];
#pragma unroll
    for (int j = 0; j < 8; ++j){
        const int k = q * 8 + j;
        pw0[j] = (short)bf_rne(w1[k * 32 + p]      * sc0);
        pw1[j] = (short)bf_rne(w1[k * 32 + 16 + p] * sc1);
    }
#pragma unroll
    for (int r = 0; r < 4; ++r){
        pc0[r] = s_bp[q * 4 + r];
        pc1[r] = s_bp[16 + q * 4 + r];
    }
#pragma unroll
    for (int i = 0; i < 8; ++i){
        const int ch = (i >> 2) * 16 + q * 4 + (i & 3);
        w2v[i]      = w2[ch * 3 + 0];
        w2v[8 + i]  = w2[ch * 3 + 1];
        w2v[16 + i] = w2[ch * 3 + 2];
    }
    const float b2v0 = b2[0], b2v1 = b2[1], b2v2 = b2[2];

    const int ngroups = (N + 31) >> 5;
    const int nw  = gridDim.x * (TPB / 64);
    const int wid = blockIdx.x * (TPB / 64) + wv;
    const int g0  = (int)((long)wid       * ngroups / nw);
    const int gE  = (int)((long)(wid + 1) * ngroups / nw);

    float* sw = &s_stage[wv][0];
    const int wrow = lane >> 3;
    const int gofs = ((lane & 7) ^ wrow) << 2;
    const int Nm1 = N - 1;
    const int e = p & 7;
    const int ra0 = p * 32        + ((((q << 1)    ) ^ e) << 2);
    const int ra1 = p * 32        + ((((q << 1) + 1) ^ e) << 2);
    const int rb0 = (16 + p) * 32 + ((((q << 1)    ) ^ e) << 2);
    const int rb1 = (16 + p) * 32 + ((((q << 1) + 1) ^ e) << 2);

#define ISSUE_GROUP(J) { \
    float* lb_ = sw + ((J) % 3) * 1024; \
    const int rbase_ = (J) << 5; \
    _Pragma("unroll") \
    for (int k_ = 0; k_ < 4; ++k_){ \
        int row_ = rbase_ + (k_ << 3) + wrow; \
        row_ = row_ < Nm1 ? row_ : Nm1; \
        gload16(feats + ((size_t)row_ << 5) + gofs, lb_ + (k_ << 8)); \
    } }

    int issued = g0;
    if (issued < gE)          { ISSUE_GROUP(issued); ++issued; }
    if (issued < gE && issued < g0 + 2){ ISSUE_GROUP(issued); ++issued; }

    for (int g = g0; g < gE; ++g){
        if (issued < gE){ ISSUE_GROUP(issued); ++issued; }
        const int ahead = issued - g - 1;
        if (ahead >= 2)      { VMWAIT(12); }
        else if (ahead == 1) { VMWAIT(8); }
        else                 { VMWAIT(0); }
        __builtin_amdgcn_sched_barrier(0);

        const float* cb = sw + (g % 3) * 1024;

        const floatx4 vA0 = *(const floatx4*)(cb + ra0);
        const floatx4 vA1 = *(const floatx4*)(cb + ra1);
        const floatx4 vB0 = *(const floatx4*)(cb + rb0);
        const floatx4 vB1 = *(const floatx4*)(cb + rb1);

        short8 bfA, bfB;
        {
            unsigned* ba = (unsigned*)&bfA;
            ba[0] = pack_bf(vA0[0], vA0[1]); ba[1] = pack_bf(vA0[2], vA0[3]);
            ba[2] = pack_bf(vA1[0], vA1[1]); ba[3] = pack_bf(vA1[2], vA1[3]);
            unsigned* bb = (unsigned*)&bfB;
            bb[0] = pack_bf(vB0[0], vB0[1]); bb[1] = pack_bf(vB0[2], vB0[3]);
            bb[2] = pack_bf(vB1[0], vB1[1]); bb[3] = pack_bf(vB1[2], vB1[3]);
        }

        const floatx4 cA0 = __builtin_amdgcn_mfma_f32_16x16x32_bf16(pw0, bfA, pc0, 0, 0, 0);
        const floatx4 cA1 = __builtin_amdgcn_mfma_f32_16x16x32_bf16(pw1, bfA, pc1, 0, 0, 0);
        const floatx4 cB0 = __builtin_amdgcn_mfma_f32_16x16x32_bf16(pw0, bfB, pc0, 0, 0, 0);
        const floatx4 cB1 = __builtin_amdgcn_mfma_f32_16x16x32_bf16(pw1, bfB, pc1, 0, 0, 0);

        float sA0 = 0.f, sA1 = 0.f, sA2 = 0.f, sB0 = 0.f, sB1 = 0.f, sB2 = 0.f;
#pragma unroll
        for (int r = 0; r < 4; ++r){
            const float a0 = fmaxf(cA0[r], 0.f);
            const float a1 = fmaxf(cA1[r], 0.f);
            sA0 = fmaf(a0, w2v[r],      sA0); sA0 = fmaf(a1, w2v[4 + r],  sA0);
            sA1 = fmaf(a0, w2v[8 + r],  sA1); sA1 = fmaf(a1, w2v[12 + r], sA1);
            sA2 = fmaf(a0, w2v[16 + r], sA2); sA2 = fmaf(a1, w2v[20 + r], sA2);
            const float b0 = fmaxf(cB0[r], 0.f);
            const float b1v = fmaxf(cB1[r], 0.f);
            sB0 = fmaf(b0, w2v[r],      sB0); sB0 = fmaf(b1v, w2v[4 + r],  sB0);
            sB1 = fmaf(b0, w2v[8 + r],  sB1); sB1 = fmaf(b1v, w2v[12 + r], sB1);
            sB2 = fmaf(b0, w2v[16 + r], sB2); sB2 = fmaf(b1v, w2v[20 + r], sB2);
        }
        sA0 += __shfl_xor(sA0, 16, 64); sA0 += __shfl_xor(sA0, 32, 64);
        sA1 += __shfl_xor(sA1, 16, 64); sA1 += __shfl_xor(sA1, 32, 64);
        sA2 += __shfl_xor(sA2, 16, 64); sA2 += __shfl_xor(sA2, 32, 64);
        sB0 += __shfl_xor(sB0, 16, 64); sB0 += __shfl_xor(sB0, 32, 64);
        sB1 += __shfl_xor(sB1, 16, 64); sB1 += __shfl_xor(sB1, 32, 64);
        sB2 += __shfl_xor(sB2, 16, 64); sB2 += __shfl_xor(sB2, 32, 64);

        const int r0 = g << 5;
        const int rA = r0 + p, rB = r0 + 16 + p;
        if (lane < 48 && rA < N){
            float val = (q == 0) ? (sA0 + b2v0) : ((q == 1) ? (sA1 + b2v1) : (sA2 + b2v2));
            pt_out[(size_t)rA * 3 + q] = val;
        }
        if (lane < 48 && rB < N){
            float val = (q == 0) ? (sB0 + b2v0) : ((q == 1) ? (sB1 + b2v1) : (sB2 + b2v2));
            pt_out[(size_t)rB * 3 + q] = val;
        }
    }
#undef ISSUE_GROUP
}

extern "C" void kernel_launch(void* const* d_in, const int* in_sizes, int n_in,
                              void* d_out, int out_size, void* d_ws, size_t ws_size,
                              hipStream_t stream) {
    const float* feats = (const float*)d_in[0];
    const int*   bidx  = (const int*)d_in[1];
    const float* w1    = (const float*)d_in[2];
    const float* b1    = (const float*)d_in[3];
    const float* gamma = (const float*)d_in[4];
    const float* beta  = (const float*)d_in[5];
    const float* w2    = (const float*)d_in[6];
    const float* b2    = (const float*)d_in[7];
    const float* mw1   = (const float*)d_in[8];
    const float* mb1   = (const float*)d_in[9];
    const float* mw2   = (const float*)d_in[10];
    const float* mb2   = (const float*)d_in[11];
    const float* iw    = (const float*)d_in[12];
    const float* ib    = (const float*)d_in[13];

    const int N = in_sizes[0] / 32;
    const int B = (out_size - 4 * N) / 33;   // out = 3N + N + 32B + B

    float* out    = (float*)d_out;
    float* pt     = out;                       // [N,3]
    float* mask   = out + (size_t)3 * N;       // [N,1]
    float* pooled = out + (size_t)4 * N;       // [B,32]
    float* iou    = pooled + (size_t)B * 32;   // [B,1]

    float* ws      = (float*)d_ws;
    float* ws_sum  = ws;                        // 32
    float* ws_sq   = ws + 32;                   // 32
    float* ws_pool = ws + 64;                   // B*32
    int*   ws_lb   = (int*)(ws + 64 + (size_t)B * 32);  // B+1 ints

    hipMemsetAsync(ws, 0, (size_t)(64 + B * 32) * sizeof(float), stream);

    lb_kernel<<<1, 64, 0, stream>>>(bidx, ws_lb, N, B);
    pass1_kernel<<<GRID_BLOCKS, TPB, 0, stream>>>(feats, ws_lb, w1, b1, mw1, mb1, mw2, mb2,
                                                  mask, ws_sum, ws_sq, ws_pool, N, B);
    pass2_kernel<<<GRID_BLOCKS, TPB, 0, stream>>>(feats, ws_lb, w1, b1, gamma, beta, w2, b2,
                                                  iw, ib, ws_sum, ws_sq, ws_pool,
                                                  pt, pooled, iou, N, B);
}